// Round 1
// baseline (54.561 us; speedup 1.0000x reference)
//
#include <hip/hip_runtime.h>

#define MXN 2048   // MX == NY == 2048
#define DD  256
#define KK  100
#define KP  128    // K padded to MFMA granularity
#define NB  8

typedef __attribute__((ext_vector_type(8))) __bf16 bf16x8;
typedef __attribute__((ext_vector_type(4))) float  f32x4;

__device__ __forceinline__ unsigned short f2b(float f) {
  union { float f; unsigned u; } v; v.f = f;
  return (unsigned short)((v.u + 0x7fffu + ((v.u >> 16) & 1u)) >> 16);
}
__device__ __forceinline__ float b2f(unsigned short h) {
  union { unsigned u; float f; } v; v.u = ((unsigned)h) << 16;
  return v.f;
}

// ---------------------------------------------------------------------------
// Kernel 1: XA = bf16(X @ A) (K padded to 128 with zeros), sqX[r] = sum_k XA[r][k]^2
// Blocks 0..127 handle X (16384 rows / 128), blocks 128..255 handle Y.
// ---------------------------------------------------------------------------
__global__ __launch_bounds__(256) void k_proj(
    const float* __restrict__ X, const float* __restrict__ Y,
    const float* __restrict__ A,
    unsigned short* __restrict__ XAo, unsigned short* __restrict__ YAo,
    float* __restrict__ sqX, float* __restrict__ sqY)
{
  __shared__ __align__(16) unsigned short Xsh[128 * 256]; // [row][d], swizzled, 64 KB
  __shared__ __align__(16) unsigned short Ash[128 * 256]; // [k][d],  swizzled, 64 KB

  const int bid = blockIdx.x;
  const bool isY = bid >= 128;
  const int row0 = (isY ? bid - 128 : bid) * 128;
  const float* __restrict__ src = isY ? Y : X;
  unsigned short* __restrict__ dst = isY ? YAo : XAo;
  float* __restrict__ sqdst = isY ? sqY : sqX;
  const int t = threadIdx.x;

  // Stage 128 rows x 256 d of input, f32 -> bf16, XOR-swizzled rows.
#pragma unroll 8
  for (int i = 0; i < 32; ++i) {
    int c4  = i * 256 + t;        // float4 index within tile (64 per row)
    int row = c4 >> 6;
    int d4  = c4 & 63;
    const float4 v = reinterpret_cast<const float4*>(src + (size_t)(row0 + row) * DD)[d4];
    unsigned long long pack =
        (unsigned long long)f2b(v.x) | ((unsigned long long)f2b(v.y) << 16) |
        ((unsigned long long)f2b(v.z) << 32) | ((unsigned long long)f2b(v.w) << 48);
    int byte = (row * 512 + d4 * 8) ^ ((row & 7) << 4);
    *reinterpret_cast<unsigned long long*>((char*)Xsh + byte) = pack;
  }
  // Stage A^T: Ash[k][d], zero-padded for k in [100,128). Thread t owns d = t.
  {
    const int d = t;
#pragma unroll 4
    for (int k = 0; k < KK; ++k) {
      unsigned short h = f2b(A[d * KK + k]);
      int byte = (k * 512 + d * 2) ^ ((k & 7) << 4);
      *reinterpret_cast<unsigned short*>((char*)Ash + byte) = h;
    }
#pragma unroll
    for (int k = KK; k < KP; ++k) {
      int byte = (k * 512 + d * 2) ^ ((k & 7) << 4);
      *reinterpret_cast<unsigned short*>((char*)Ash + byte) = 0;
    }
  }
  __syncthreads();

  const int w  = t >> 6, l = t & 63;
  const int lr = l & 15, lk = (l >> 4) * 8;
  const int wr0 = w * 32;   // wave handles 32 rows x all 128 k-outputs

  f32x4 acc[2][8];
#pragma unroll
  for (int i = 0; i < 2; ++i)
#pragma unroll
    for (int j = 0; j < 8; ++j) acc[i][j] = (f32x4){0.f, 0.f, 0.f, 0.f};

#pragma unroll
  for (int ks = 0; ks < 8; ++ks) {
    const int d = ks * 32 + lk;
    int r0 = wr0 + lr;
    int r1 = wr0 + 16 + lr;
    bf16x8 a0 = *reinterpret_cast<bf16x8*>((char*)Xsh + ((r0 * 512 + d * 2) ^ ((r0 & 7) << 4)));
    bf16x8 a1 = *reinterpret_cast<bf16x8*>((char*)Xsh + ((r1 * 512 + d * 2) ^ ((r1 & 7) << 4)));
#pragma unroll
    for (int nf = 0; nf < 8; ++nf) {
      int kq = nf * 16 + lr;
      bf16x8 bf = *reinterpret_cast<bf16x8*>((char*)Ash + ((kq * 512 + d * 2) ^ ((kq & 7) << 4)));
      acc[0][nf] = __builtin_amdgcn_mfma_f32_16x16x32_bf16(a0, bf, acc[0][nf], 0, 0, 0);
      acc[1][nf] = __builtin_amdgcn_mfma_f32_16x16x32_bf16(a1, bf, acc[1][nf], 0, 0, 0);
    }
  }

  // Epilogue: quantize to bf16, store XA, accumulate row sums of squares.
  float sq[2][4] = {{0.f,0.f,0.f,0.f},{0.f,0.f,0.f,0.f}};
#pragma unroll
  for (int mf = 0; mf < 2; ++mf)
#pragma unroll
    for (int nf = 0; nf < 8; ++nf)
#pragma unroll
      for (int reg = 0; reg < 4; ++reg) {
        float v = acc[mf][nf][reg];
        unsigned short h = f2b(v);
        float vq = b2f(h);
        int r = row0 + wr0 + mf * 16 + ((l >> 4) << 2) + reg;
        dst[(size_t)r * KP + nf * 16 + lr] = h;
        sq[mf][reg] += vq * vq;
      }
#pragma unroll
  for (int mf = 0; mf < 2; ++mf)
#pragma unroll
    for (int reg = 0; reg < 4; ++reg) {
      float s = sq[mf][reg];
      s += __shfl_xor(s, 1);
      s += __shfl_xor(s, 2);
      s += __shfl_xor(s, 4);
      s += __shfl_xor(s, 8);
      if (lr == 0)
        sqdst[row0 + wr0 + mf * 16 + ((l >> 4) << 2) + reg] = s;
    }
}

// ---------------------------------------------------------------------------
// Kernel 2: out[b][n][m] = relu(sqY[n] + sqX[m] - 2 * sum_k YA[n][k]*XA[m][k])
// 128x128 output tile per block; 4 waves each 64x64; K = 128 (4 MFMA steps).
// ---------------------------------------------------------------------------
__global__ __launch_bounds__(256) void k_cross(
    const unsigned short* __restrict__ XA, const unsigned short* __restrict__ YA,
    const float* __restrict__ sqX, const float* __restrict__ sqY,
    float* __restrict__ out)
{
  __shared__ __align__(16) unsigned short Ysh[128 * 128]; // [n][k], swizzled, 32 KB
  __shared__ __align__(16) unsigned short Xsh[128 * 128]; // [m][k], swizzled, 32 KB

  const int bid = blockIdx.x;
  const int b  = bid >> 8;          // 256 tiles per batch
  const int tb = bid & 255;
  const int n0 = (tb >> 4) * 128;
  const int m0 = (tb & 15) * 128;
  const int t = threadIdx.x;

#pragma unroll
  for (int i = 0; i < 8; ++i) {
    int ch = i * 256 + t;           // 16 chunks of 8 bf16 per row
    int row = ch >> 4, c = ch & 15;
    bf16x8 vy = *reinterpret_cast<const bf16x8*>(YA + ((size_t)(b * MXN + n0 + row) * KP + c * 8));
    bf16x8 vx = *reinterpret_cast<const bf16x8*>(XA + ((size_t)(b * MXN + m0 + row) * KP + c * 8));
    int byte = (row * 256 + c * 16) ^ ((row & 7) << 4);
    *reinterpret_cast<bf16x8*>((char*)Ysh + byte) = vy;
    *reinterpret_cast<bf16x8*>((char*)Xsh + byte) = vx;
  }
  __syncthreads();

  const int w  = t >> 6, l = t & 63;
  const int nr0 = (w & 1) * 64;     // wave's n-offset within tile
  const int mc0 = (w >> 1) * 64;    // wave's m-offset within tile
  const int lr = l & 15, lk = (l >> 4) * 8;

  f32x4 acc[4][4];
#pragma unroll
  for (int i = 0; i < 4; ++i)
#pragma unroll
    for (int j = 0; j < 4; ++j) acc[i][j] = (f32x4){0.f, 0.f, 0.f, 0.f};

#pragma unroll
  for (int ks = 0; ks < 4; ++ks) {
    const int d = ks * 32 + lk;
    bf16x8 afr[4], bfr[4];
#pragma unroll
    for (int i = 0; i < 4; ++i) {
      int rn = nr0 + i * 16 + lr;
      afr[i] = *reinterpret_cast<bf16x8*>((char*)Ysh + ((rn * 256 + d * 2) ^ ((rn & 7) << 4)));
      int rm = mc0 + i * 16 + lr;
      bfr[i] = *reinterpret_cast<bf16x8*>((char*)Xsh + ((rm * 256 + d * 2) ^ ((rm & 7) << 4)));
    }
#pragma unroll
    for (int i = 0; i < 4; ++i)
#pragma unroll
      for (int j = 0; j < 4; ++j)
        acc[i][j] = __builtin_amdgcn_mfma_f32_16x16x32_bf16(afr[i], bfr[j], acc[i][j], 0, 0, 0);
  }

  float sx[4];
#pragma unroll
  for (int j = 0; j < 4; ++j) sx[j] = sqX[b * MXN + m0 + mc0 + j * 16 + lr];

#pragma unroll
  for (int i = 0; i < 4; ++i)
#pragma unroll
    for (int reg = 0; reg < 4; ++reg) {
      int n = n0 + nr0 + i * 16 + ((l >> 4) << 2) + reg;
      float sy = sqY[b * MXN + n];
      size_t obase = ((size_t)b * MXN + n) * MXN + m0 + mc0;
#pragma unroll
      for (int j = 0; j < 4; ++j) {
        float v = sy + sx[j] - 2.0f * acc[i][j][reg];
        out[obase + j * 16 + lr] = v > 0.f ? v : 0.f;
      }
    }
}

extern "C" void kernel_launch(void* const* d_in, const int* in_sizes, int n_in,
                              void* d_out, int out_size, void* d_ws, size_t ws_size,
                              hipStream_t stream) {
  const float* X = (const float*)d_in[0];   // (8, 2048, 256)
  const float* Y = (const float*)d_in[1];   // (8, 2048, 256)
  const float* A = (const float*)d_in[2];   // (256, 100)
  float* out = (float*)d_out;               // (8, 2048, 2048)

  char* ws = (char*)d_ws;
  const size_t ROWS = (size_t)NB * MXN;     // 16384
  unsigned short* XAw = (unsigned short*)ws;                        // 4 MB
  unsigned short* YAw = (unsigned short*)(ws + ROWS * KP * 2);      // 4 MB
  float* sqX = (float*)(ws + 2 * ROWS * KP * 2);                    // 64 KB
  float* sqY = (float*)(ws + 2 * ROWS * KP * 2 + ROWS * 4);         // 64 KB

  k_proj<<<256, 256, 0, stream>>>(X, Y, A, XAw, YAw, sqX, sqY);
  k_cross<<<NB * 256, 256, 0, stream>>>(XAw, YAw, sqX, sqY, out);
}